// Round 6
// baseline (112.091 us; speedup 1.0000x reference)
//
#include <hip/hip_runtime.h>
#include <hip/hip_bf16.h>
#include <math.h>

// SemiCRF dense span scores, MI355X gfx950.  Round 6: two-kernel, LDS-free hot loop.
// K1 (29 blocks): global prefix sums c1/c2 (8193x28 f32) in d_ws via per-feature
//   block scan; zero cols 26/27; pack W1^T MFMA-fragment table (b1 folded in as a
//   constant-1.0 input column), W2 quad table, len/loglen LUT.
// K2 (2048x256, NO shared memory, NO barriers): each wave owns one i; 7 l-chunks:
//   4 global b128 c-quad loads -> register agg build (same k-map as W1 table, so
//   HW k-pairing cancels) -> 8x mfma_f32_16x16x32_bf16 -> f32 epilogue (relu,
//   W2 dot, 2 shfl reduce over q), lanes<16 store.

typedef __attribute__((ext_vector_type(4))) float f32x4;
typedef __attribute__((ext_vector_type(8))) short bf16x8;
typedef __attribute__((ext_vector_type(4))) unsigned int u32x4;

#define L_SEQ 8192
#define F_DIM 26
#define SEG 100
#define HID 64
#define CSTR 28                             /* f32 per c-row, 16B multiple */
#define NROW (L_SEQ + 1)

#define C1_OFF 0
#define C2_OFF (NROW * CSTR * 4)            /* 917,616 (16B-aligned) */
#define WF_OFF (2 * NROW * CSTR * 4)        /* 1,835,232 */
#define W2_OFF (WF_OFF + 64 * 128)          /* + 8 KiB  */
#define LEN_OFF (W2_OFF + 64 * 64)          /* + 4 KiB  */

__device__ __forceinline__ unsigned short f2bf(float v) {
    unsigned u = __builtin_bit_cast(unsigned, v);
    u += 0x7FFFu + ((u >> 16) & 1u);   // round-to-nearest-even
    return (unsigned short)(u >> 16);
}
__device__ __forceinline__ unsigned pk(unsigned short a, unsigned short b) {
    return (unsigned)a | ((unsigned)b << 16);
}
__device__ __forceinline__ unsigned cvtpk(float lo, float hi) {
    unsigned r;
    asm("v_cvt_pk_bf16_f32 %0, %1, %2" : "=v"(r) : "v"(lo), "v"(hi));
    return r;
}

// ---------------- K1: prefix sums + weight tables ----------------
__global__ __launch_bounds__(256)
void semicrf_prep(const float* __restrict__ x, const float* __restrict__ W1,
                  const float* __restrict__ b1, const float* __restrict__ W2,
                  char* __restrict__ ws) {
    const int blk = blockIdx.x;
    const int tid = threadIdx.x;
    float* c1 = (float*)(ws + C1_OFF);
    float* c2 = (float*)(ws + C2_OFF);

    if (blk < 26) {
        const int f = blk;
        // phase 1: per-thread partial sums over 32 rows
        const int r0 = tid * 32;
        float s1 = 0.f, s2 = 0.f;
#pragma unroll 4
        for (int k = 0; k < 32; ++k) {
            float v = x[(r0 + k) * F_DIM + f];
            s1 += v;
            s2 = fmaf(v, v, s2);
        }
        // phase 2: block exclusive scan (wave shfl_up + LDS carry)
        const int lane = tid & 63, wv = tid >> 6;
        float in1 = s1, in2 = s2;
#pragma unroll
        for (int d = 1; d < 64; d <<= 1) {
            float t1 = __shfl_up(in1, d);
            float t2 = __shfl_up(in2, d);
            if (lane >= d) { in1 += t1; in2 += t2; }
        }
        __shared__ float wsum1[4], wsum2[4];
        if (lane == 63) { wsum1[wv] = in1; wsum2[wv] = in2; }
        __syncthreads();
        float base1 = in1 - s1, base2 = in2 - s2;
        for (int w = 0; w < wv; ++w) { base1 += wsum1[w]; base2 += wsum2[w]; }
        // phase 3: re-walk, writing global prefixes (row 0 = 0)
        if (tid == 0) { c1[f] = 0.f; c2[f] = 0.f; }
        s1 = base1; s2 = base2;
#pragma unroll 4
        for (int k = 0; k < 32; ++k) {
            const int rr = r0 + k;
            float v = x[rr * F_DIM + f];
            s1 += v;
            s2 = fmaf(v, v, s2);
            c1[(rr + 1) * CSTR + f] = s1;
            c2[(rr + 1) * CSTR + f] = s2;
        }
    } else if (blk < 28) {
        const int f = blk;   // zero pad columns 26, 27 (read by q==2 quads)
        for (int row = tid; row < NROW; row += 256) {
            c1[row * CSTR + f] = 0.f;
            c2[row * CSTR + f] = 0.f;
        }
    } else {
        // weight tables
        unsigned* lenlt = (unsigned*)(ws + LEN_OFF);
        if (tid < 128) {
            float lf = (float)(tid + 1);
            lenlt[tid] = pk(f2bf(lf * 0.002f), f2bf(logf(lf + 1e-6f) * (1.0f / 6.0f)));
        }
        if (tid < 64) {
            const int r = tid & 15, q = tid >> 4;
            // k-map (q, elem j), s=0 -> a0, s=1 -> a1:
            //  q<3 : j<4 -> f=4q+j ; j>=4 -> f=16+4q+(j-4) (f>=26 zero)
            //        s=0: mean (wr=f), s=1: var (wr=26+f)
            //  q=3 : j<4 -> f=12+j ; s=0 j=4 -> len(52), j=5 -> loglen(53),
            //        j=6 -> b1 (constant-1.0 input column); all else zero.
            for (int s = 0; s < 2; ++s)
                for (int t = 0; t < 4; ++t) {
                    bf16x8 v;
                    for (int j = 0; j < 8; ++j) {
                        float wv_ = 0.f;
                        if (q < 3 || j < 4) {
                            int f = (j < 4) ? (4 * q + j) : (16 + 4 * q + (j - 4));
                            if (f < 26) wv_ = W1[((s == 0) ? f : 26 + f) * HID + (t * 16 + r)];
                        } else if (s == 0 && j == 4) wv_ = W1[52 * HID + (t * 16 + r)];
                        else if (s == 0 && j == 5)   wv_ = W1[53 * HID + (t * 16 + r)];
                        else if (s == 0 && j == 6)   wv_ = b1[t * 16 + r];
                        v[j] = (short)f2bf(wv_);
                    }
                    *(bf16x8*)(ws + WF_OFF + tid * 128 + (s * 4 + t) * 16) = v;
                }
            for (int t = 0; t < 4; ++t)
                *(f32x4*)(ws + W2_OFF + tid * 64 + t * 16) =
                    *(const f32x4*)(W2 + t * 16 + q * 4);
        }
    }
}

// ---------------- K2: main compute (no LDS, no barriers) ----------------
__global__ __launch_bounds__(256, 4)
void semicrf_main(const char* __restrict__ ws, const float* __restrict__ b2p,
                  float* __restrict__ out) {
    const int tid = threadIdx.x;
    const int lane = tid & 63;
    const int wv = tid >> 6;
    const int i = blockIdx.x * 4 + wv;      // one i per wave
    const int r = lane & 15, q = lane >> 4;

    const float* c1 = (const float*)(ws + C1_OFF);
    const float* c2 = (const float*)(ws + C2_OFF);
    const unsigned* lenlt = (const unsigned*)(ws + LEN_OFF);

    bf16x8 wf[8];                            // wf[s*4+t]
#pragma unroll
    for (int k = 0; k < 8; ++k)
        wf[k] = *(const bf16x8*)(ws + WF_OFF + lane * 128 + k * 16);
    f32x4 w2v[4];
#pragma unroll
    for (int t = 0; t < 4; ++t)
        w2v[t] = *(const f32x4*)(ws + W2_OFF + lane * 64 + t * 16);
    const float b2v = b2p[0];

    const int f0A = 4 * q;
    const int f0B = 16 + 4 * q;              // only q<3
    const float* c1b = c1 + i * CSTR;
    const float* c2b = c2 + i * CSTR;
    const f32x4 c1iA = *(const f32x4*)(c1b + f0A);
    const f32x4 c2iA = *(const f32x4*)(c2b + f0A);
    f32x4 c1iB = {0.f, 0.f, 0.f, 0.f}, c2iB = {0.f, 0.f, 0.f, 0.f};
    if (q < 3) {
        c1iB = *(const f32x4*)(c1b + f0B);
        c2iB = *(const f32x4*)(c2b + f0B);
    }

    for (int lc = 0; lc < 7; ++lc) {
        const int l_seg = lc * 16 + 1 + r;               // this lane's length
        const float inv_l = __builtin_amdgcn_rcpf((float)l_seg);
        const int cj = min(i + l_seg, L_SEQ);            // clamp junk (l>100)
        const float* c1j = c1 + cj * CSTR;
        const float* c2j = c2 + cj * CSTR;

        union { u32x4 u; bf16x8 h; } A0, A1;
        {   // quad A: f = f0A..f0A+3 (all lanes)
            f32x4 m = (*(const f32x4*)(c1j + f0A) - c1iA) * inv_l;
            f32x4 t = (*(const f32x4*)(c2j + f0A) - c2iA) * inv_l;
            f32x4 v = t - m * m;
            A0.u.x = cvtpk(m[0], m[1]);
            A0.u.y = cvtpk(m[2], m[3]);
            A1.u.x = cvtpk(v[0], v[1]);
            A1.u.y = cvtpk(v[2], v[3]);
        }
        if (q < 3) {   // quad B: f = f0B..f0B+3 (cols 26,27 are zero)
            f32x4 m = (*(const f32x4*)(c1j + f0B) - c1iB) * inv_l;
            f32x4 t = (*(const f32x4*)(c2j + f0B) - c2iB) * inv_l;
            f32x4 v = t - m * m;
            A0.u.z = cvtpk(m[0], m[1]);
            A0.u.w = cvtpk(m[2], m[3]);
            A1.u.z = cvtpk(v[0], v[1]);
            A1.u.w = cvtpk(v[2], v[3]);
        } else {       // len/loglen at elems 4,5; 1.0 (b1 column) at elem 6
            A0.u.z = lenlt[lc * 16 + r];
            A0.u.w = 0x00003F80u;           // bf16(1.0) low, 0 high
            A1.u.z = 0u;
            A1.u.w = 0u;
        }

        f32x4 acc0 = {0.f, 0.f, 0.f, 0.f};
        f32x4 acc1 = {0.f, 0.f, 0.f, 0.f};
        f32x4 acc2 = {0.f, 0.f, 0.f, 0.f};
        f32x4 acc3 = {0.f, 0.f, 0.f, 0.f};
        acc0 = __builtin_amdgcn_mfma_f32_16x16x32_bf16(wf[0], A0.h, acc0, 0, 0, 0);
        acc1 = __builtin_amdgcn_mfma_f32_16x16x32_bf16(wf[1], A0.h, acc1, 0, 0, 0);
        acc2 = __builtin_amdgcn_mfma_f32_16x16x32_bf16(wf[2], A0.h, acc2, 0, 0, 0);
        acc3 = __builtin_amdgcn_mfma_f32_16x16x32_bf16(wf[3], A0.h, acc3, 0, 0, 0);
        acc0 = __builtin_amdgcn_mfma_f32_16x16x32_bf16(wf[4], A1.h, acc0, 0, 0, 0);
        acc1 = __builtin_amdgcn_mfma_f32_16x16x32_bf16(wf[5], A1.h, acc1, 0, 0, 0);
        acc2 = __builtin_amdgcn_mfma_f32_16x16x32_bf16(wf[6], A1.h, acc2, 0, 0, 0);
        acc3 = __builtin_amdgcn_mfma_f32_16x16x32_bf16(wf[7], A1.h, acc3, 0, 0, 0);

        // epilogue: p = sum_t sum_g relu(h) * w2 (b1 already inside h)
        float p0 = 0.f, p1 = 0.f, p2 = 0.f, p3 = 0.f;
#define EPI(ACC, PT, T)                                             \
        PT = fmaf(fmaxf(ACC[0], 0.f), w2v[T][0], PT);               \
        PT = fmaf(fmaxf(ACC[1], 0.f), w2v[T][1], PT);               \
        PT = fmaf(fmaxf(ACC[2], 0.f), w2v[T][2], PT);               \
        PT = fmaf(fmaxf(ACC[3], 0.f), w2v[T][3], PT);
        EPI(acc0, p0, 0) EPI(acc1, p1, 1) EPI(acc2, p2, 2) EPI(acc3, p3, 3)
#undef EPI
        float p = (p0 + p1) + (p2 + p3);
        p += __shfl_xor(p, 16);              // reduce over q (4 k-groups)
        p += __shfl_xor(p, 32);

        if (lane < 16) {
            const int l = lc * 16 + 1 + r;
            if (l <= SEG)
                out[i * SEG + (l - 1)] = (i + l <= L_SEQ) ? p + b2v : 0.0f;
        }
    }
}

extern "C" void kernel_launch(void* const* d_in, const int* in_sizes, int n_in,
                              void* d_out, int out_size, void* d_ws, size_t ws_size,
                              hipStream_t stream) {
    const float* x  = (const float*)d_in[0];
    const float* W1 = (const float*)d_in[1];
    const float* b1 = (const float*)d_in[2];
    const float* W2 = (const float*)d_in[3];
    const float* b2 = (const float*)d_in[4];
    float* out = (float*)d_out;
    char* ws = (char*)d_ws;

    semicrf_prep<<<dim3(29), dim3(256), 0, stream>>>(x, W1, b1, W2, ws);
    semicrf_main<<<dim3(L_SEQ / 4), dim3(256), 0, stream>>>(ws, b2, out);
}